// Round 3
// baseline (49.245 us; speedup 1.0000x reference)
//
#include <hip/hip_runtime.h>
#include <math.h>

// EdgeAwareLoss — round 6: stream/stencil separation.
//
// r5 post-mortem: cutting SWAR VALU 3x changed nothing -> edge kernel was
// bound by its TILED pred read (128-256B chunks at 4KB row stride ~= 2 TB/s
// effective HBM), not by VALU. r6 makes every 64MB stream LINEAR:
//   1. binarize: target (linear 64MB) -> 1 bit/px          (~10.5us, BW)
//   2. edge_mask: bit-sliced Canny on packed bits only     (~3-7us, tiny)
//      -> edge-zone bits, column-band-major (coalesced stores)
//   3. bce: pred (linear 64MB) + tbits + ezbits -> partials (~11-13us, BW)
//   4. finalize
//
// Exactness (absmax 0.0 in r1-r5 with identical integer pipeline):
//  - img=(t>0.5)*255 => m multiple of 255 => weak==strong => strong==cand.
//  - gx,gy in [-4,4] (255-units), m=|gx|+|gy|<=6: 3 bit-planes.
//  - horiz: ay==0&&ax>=1 || ay==1&&ax>=3 ; vert: ax==0&&ay>=1 || ax==1&&ay>=3
//  - NMS row trick: P=(m>left); kH = P & ~(P>>1).
//  - bce = -max(log(t?p:1-p),-100); 1-p exact for p>=0.5 (Sterbenz).

typedef unsigned long long u64;
typedef unsigned int u32;

#define NT 128
#define H_IMG 1024
#define W_IMG 1024
#define WPR 32                 // packed u32 words per image row

// ---- kernel 1: binarize target to 1 bit/px (plain bit order) ----
__global__ __launch_bounds__(256)
void binarize_kernel(const float* __restrict__ target, u32* __restrict__ packed,
                     int nwords)
{
    int t = blockIdx.x * 256 + threadIdx.x;
    if (t >= nwords) return;
    const float4* src = (const float4*)target + (size_t)t * 8;
    u32 v = 0;
#pragma unroll
    for (int k = 0; k < 8; ++k) {
        float4 f = src[k];
        v |= (f.x > 0.5f ? 1u : 0u) << (4 * k);
        v |= (f.y > 0.5f ? 2u : 0u) << (4 * k);
        v |= (f.z > 0.5f ? 4u : 0u) << (4 * k);
        v |= (f.w > 0.5f ? 8u : 0u) << (4 * k);
    }
    packed[t] = v;
}

// unsigned 3-bit bit-sliced compare: plane of (a > b)
__device__ __forceinline__ u64 gt3(u64 a2, u64 a1, u64 a0,
                                   u64 b2, u64 b1, u64 b0)
{
    u64 e2 = ~(a2 ^ b2), g2 = a2 & ~b2;
    u64 e1 = ~(a1 ^ b1), g1 = a1 & ~b1;
    u64 g0 = a0 & ~b0;
    return g2 | (e2 & (g1 | (e1 & g0)));
}

// ---- kernel 2: bit-sliced Canny -> edge-zone bits (no pred stream) ----
// Tile 32 cols x 64 rows. Output layout column-band-major:
//   ezb[((bz*32 + bx) << 10) | row]  (consecutive rows -> coalesced stores)
__global__ __launch_bounds__(NT)
void edge_mask_kernel(const u32* __restrict__ packed, u32* __restrict__ ezb)
{
    __shared__ u64 bl[72];                    // bit j = col c0-4+j
    __shared__ u64 m0[70], m1[70], m2[70];    // m planes, row tr = idx+1
    __shared__ u64 hz[70], vt[70], sdp[70];   // class planes
    __shared__ u64 hr[68];                    // horiz 5-OR of cand, row tr = idx+2

    const int tid = threadIdx.x;
    const int bx = blockIdx.x;
    const int bz = blockIdx.z;
    const int r0 = blockIdx.y * 64;
    const u32* pb = packed + (size_t)bz * H_IMG * WPR;

    // ---- Stage 0: packed bits -> 40-bit row windows, edge-replicate clamp
    if (tid < 72) {
        int r = r0 - 4 + tid; r = r < 0 ? 0 : (r > H_IMG - 1 ? H_IMG - 1 : r);
        const u32* prow = pb + (size_t)r * WPR;
        u32 wB = prow[bx];
        u32 wA = (bx > 0) ? prow[bx - 1] : ((wB & 1u) ? ~0u : 0u);
        u32 wC = (bx + 1 < WPR) ? prow[bx + 1] : ((wB >> 31) ? ~0u : 0u);
        bl[tid] = (u64)(wA >> 28) | ((u64)wB << 4) | ((u64)(wC & 0xFu) << 36);
    }
    __syncthreads();

    // ---- Stage A: bit-sliced Sobel -> m planes + class planes (rows 1..70)
    if (tid < 70) {
        const int tr = tid + 1;
        u64 A = bl[tr - 1], Bq = bl[tr], C = bl[tr + 1];
        u64 AL = A << 1, AR = A >> 1;
        u64 BL = Bq << 1, BR = Bq >> 1;
        u64 CL = C << 1, CR = C >> 1;

        u64 sx = AR ^ CR, cxk = AR & CR;
        u64 Px1 = BR ^ cxk, Px2 = BR & cxk;
        u64 sn = AL ^ CL, cnk = AL & CL;
        u64 Nx1 = BL ^ cnk, Nx2 = BL & cnk;
        u64 d0 = sx ^ sn;
        u64 ca = sx | ~sn;
        u64 nb1 = ~Nx1, t1 = Px1 ^ nb1, d1 = t1 ^ ca;
        u64 cb = (Px1 & nb1) | (ca & t1);
        u64 nb2 = ~Nx2, t2 = Px2 ^ nb2, d2 = t2 ^ cb;
        u64 cc = (Px2 & nb2) | (cb & t2);
        u64 sgx = ~cc;                         // gx < 0
        u64 ax0 = d0;
        u64 ax1 = d1 ^ (sgx & d0);
        u64 ax2 = d2 ^ (sgx & (d0 | d1));

        u64 sy = CL ^ CR, cyk = CL & CR;
        u64 Py1 = C ^ cyk, Py2 = C & cyk;
        u64 sm = AL ^ AR, cmk = AL & AR;
        u64 Ny1 = A ^ cmk, Ny2 = A & cmk;
        u64 e0 = sy ^ sm;
        u64 ka = sy | ~sm;
        u64 mb1 = ~Ny1, u1 = Py1 ^ mb1, f1 = u1 ^ ka;
        u64 kb = (Py1 & mb1) | (ka & u1);
        u64 mb2 = ~Ny2, u2 = Py2 ^ mb2, f2 = u2 ^ kb;
        u64 kc = (Py2 & mb2) | (kb & u2);
        u64 sgy = ~kc;                         // gy < 0
        u64 ay0 = e0;
        u64 ay1 = f1 ^ (sgy & e0);
        u64 ay2 = f2 ^ (sgy & (e0 | f1));

        u64 s0 = ax0 ^ ay0, q0 = ax0 & ay0;
        u64 tt = ax1 ^ ay1, s1 = tt ^ q0;
        u64 q1 = (ax1 & ay1) | (q0 & tt);
        u64 s2 = ax2 ^ ay2 ^ q1;
        m0[tid] = s0; m1[tid] = s1; m2[tid] = s2;

        u64 ax12 = ax1 | ax2, axnz = ax0 | ax12;
        u64 axe1 = ax0 & ~ax12, axg3 = ax2 | (ax1 & ax0);
        u64 ay12 = ay1 | ay2, aynz = ay0 | ay12;
        u64 aye1 = ay0 & ~ay12, ayg3 = ay2 | (ay1 & ay0);
        hz[tid] = (axnz & ~aynz) | (aye1 & axg3);
        vt[tid] = (aynz & ~axnz) | (axe1 & ayg3);
        u64 gxp = axnz & ~sgx, gyp = aynz & ~sgy;
        sdp[tid] = (gxp & sgy) | (sgx & gyp);
    }
    __syncthreads();

    // ---- Stage B: bit-sliced NMS + threshold + interior; fused horiz 5-OR
    if (tid < 68) {
        const int i = tid + 1;
        u64 M0 = m0[i], M1 = m1[i], M2 = m2[i];
        u64 U0 = m0[i - 1], U1 = m1[i - 1], U2 = m2[i - 1];
        u64 D0 = m0[i + 1], D1 = m1[i + 1], D2 = m2[i + 1];
        u64 H = hz[i], V = vt[i], S = sdp[i];

        u64 P = gt3(M2, M1, M0, M2 << 1, M1 << 1, M0 << 1);   // m > left
        u64 kH = P & ~(P >> 1);
        u64 gMU = gt3(M2, M1, M0, U2, U1, U0);
        u64 gDM = gt3(D2, D1, D0, M2, M1, M0);
        u64 kV = gMU & ~gDM;
        u64 gMUR = gt3(M2, M1, M0, U2 >> 1, U1 >> 1, U0 >> 1);
        u64 gDLM = gt3(D2 << 1, D1 << 1, D0 << 1, M2, M1, M0);
        u64 kA = gMUR & ~gDLM;
        u64 gMUL = gt3(M2, M1, M0, U2 << 1, U1 << 1, U0 << 1);
        u64 gDRM = gt3(D2 >> 1, D1 >> 1, D0 >> 1, M2, M1, M0);
        u64 kB = gMUL & ~gDRM;

        u64 nHV = ~(H | V);
        u64 keep = (H & kH) | (V & kV) | (nHV & ((S & kA) | (~S & kB)));
        u64 nz = M0 | M1 | M2;
        u64 colmask = (~0ULL << ((bx == 0) ? 5 : 2)) &
                      (~0ULL >> (63 - ((bx == 31) ? 34 : 37)));
        u64 cand = keep & nz & colmask;
        int rr = r0 - 2 + tid;
        if (rr < 1 || rr > H_IMG - 2) cand = 0;
        hr[tid] = cand | (cand << 1) | (cand << 2) | (cand >> 1) | (cand >> 2);
    }
    __syncthreads();

    // ---- Stage C: vertical 5-OR -> edge-zone word, coalesced store ----
    if (tid < 64) {
        u64 ez = hr[tid] | hr[tid + 1] | hr[tid + 2] | hr[tid + 3] | hr[tid + 4];
        ezb[(((size_t)bz * 32 + bx) << 10) | (u32)(r0 + tid)] = (u32)(ez >> 4);
    }
}

// ---- kernel 3: linear weighted-BCE stream ----
__global__ __launch_bounds__(256)
void bce_kernel(const float* __restrict__ pred,
                const u32* __restrict__ tbits,
                const u32* __restrict__ ezb,
                float* __restrict__ partials, int n4)
{
    __shared__ float wsum[4];
    const int tid = threadIdx.x;
    const int gid = blockIdx.x * 256 + tid;
    const int nth = gridDim.x * 256;
    const int iters = n4 / nth;
    const int rem = n4 - iters * nth;
    const float4* p4 = (const float4*)pred;

    float acc = 0.0f;
    int i4 = gid;
    for (int it = 0; it < iters + 1; ++it, i4 += nth) {
        if (it == iters && gid >= rem) break;
        float4 pv = p4[i4];
        u32 px0 = (u32)i4 << 2;
        u32 sh = px0 & 31u;
        u32 tw = tbits[i4 >> 3] >> sh;
        u32 ew = ezb[((((px0 >> 20) << 5) | ((px0 >> 5) & 31u)) << 10)
                     | ((px0 >> 10) & 1023u)] >> sh;
        float ps[4] = {pv.x, pv.y, pv.z, pv.w};
#pragma unroll
        for (int k = 0; k < 4; ++k) {
            float p = ps[k];
            float xx = ((tw >> k) & 1u) ? p : 1.0f - p;
            float lg = fmaxf(__logf(xx), -100.0f);
            acc = fmaf(((ew >> k) & 1u) ? 5.0f : 1.0f, -lg, acc);
        }
    }

    for (int off = 32; off > 0; off >>= 1)
        acc += __shfl_down(acc, off);
    int wid = tid >> 6, lane = tid & 63;
    if (lane == 0) wsum[wid] = acc;
    __syncthreads();
    if (tid == 0)
        partials[blockIdx.x] = wsum[0] + wsum[1] + wsum[2] + wsum[3];
}

__global__ __launch_bounds__(256)
void finalize_kernel(const float* __restrict__ partials, float* __restrict__ out,
                     int nblocks, double invN)
{
    __shared__ double ws[4];
    double s = 0.0;
    for (int i = threadIdx.x; i < nblocks; i += 256) s += (double)partials[i];
    for (int off = 32; off > 0; off >>= 1) s += __shfl_down(s, off);
    int wid = threadIdx.x >> 6, lane = threadIdx.x & 63;
    if (lane == 0) ws[wid] = s;
    __syncthreads();
    if (threadIdx.x == 0) out[0] = (float)((ws[0] + ws[1] + ws[2] + ws[3]) * invN);
}

extern "C" void kernel_launch(void* const* d_in, const int* in_sizes, int n_in,
                              void* d_out, int out_size, void* d_ws, size_t ws_size,
                              hipStream_t stream)
{
    (void)n_in; (void)out_size; (void)ws_size;
    const float* pred   = (const float*)d_in[0];
    const float* target = (const float*)d_in[1];
    const int N = in_sizes[0];
    const int B = N / (H_IMG * W_IMG);

    // ws layout: [0,32KB) partials; [32KB, +2MB) target bits; then ez bits
    float* partials = (float*)d_ws;
    u32* tbits = (u32*)((char*)d_ws + 32768);
    u32* ezb   = (u32*)((char*)d_ws + 32768 + (size_t)B * H_IMG * WPR * 4);
    const int nwords = B * H_IMG * WPR;          // 2 MB of bits for B=16

    binarize_kernel<<<(nwords + 255) / 256, 256, 0, stream>>>(target, tbits, nwords);

    dim3 grid(W_IMG / 32, H_IMG / 64, B);
    edge_mask_kernel<<<grid, NT, 0, stream>>>(tbits, ezb);

    const int NB_BCE = 2048;
    bce_kernel<<<NB_BCE, 256, 0, stream>>>(pred, tbits, ezb, partials, N / 4);

    finalize_kernel<<<1, 256, 0, stream>>>(partials, (float*)d_out, NB_BCE,
                                           1.0 / (double)N);
}

// Round 4
// 45.305 us; speedup vs baseline: 1.0870x; 1.0870x over previous
//
#include <hip/hip_runtime.h>
#include <math.h>

// EdgeAwareLoss — round 7: full-width row bands, single fused kernel.
//
// r3-r6 evidence: tiled (64-col) pred reads run at ~2 TB/s (r4: 101MB/57us);
// linear streams run at 6.7 TB/s (binarize, harness fills); extra kernel
// boundaries cost us (r6: 4 kernels > r3: 3 kernels despite linear bce).
// r7: stencil tile = 32 FULL ROWS x 1024 cols. Every heavy stream is a
// contiguous slab (target: 40 rows x 4KB, pred: 32 rows x 4KB). Vertical
// halo (25%) is L3-absorbed (64MB target << 256MB L3). One kernel; the
// final reduction uses threadfence + atomic counter (last block reduces).
//
// Exactness vs JAX reference (bit-sliced pipeline validated absmax 0.0 in
// r5/r6; identical integer math, new window geometry):
//  - img=(t>0.5)*255 => m multiple of 255 => weak==strong => strong==cand.
//  - gx,gy in [-4,4] (255-units), m=|gx|+|gy|<=6: 3 bit-planes.
//  - horiz: ay==0&&ax>=1 || ay==1&&ax>=3 ; vert: ax==0&&ay>=1 || ax==1&&ay>=3
//  - Row bit j of word w = col 64w+j; cross-word shifts carry 1-2 bits from
//    neighbor words; image borders (w=0 bit0 / w=15 bit63) use edge-replicate
//    for Sobel, and cand is masked to interior cols/rows anyway.
//  - Horizontal dilate uses 0 outside the image (cl/cr=0 at row ends) ==
//    reduce_window 0-pad. Vertical dilate: halo cand rows computed, rows
//    outside [1,1022] masked to 0.
//  - bce = -max(log(t?p:1-p),-100); 1-p exact for p>=0.5 (Sterbenz).

typedef unsigned long long u64;
typedef unsigned int u32;
typedef unsigned char u8;

#define NT 512
#define RB 32                  // rows per band
#define H_IMG 1024
#define W_IMG 1024
#define NBANDS (H_IMG / RB)    // 32

__device__ __forceinline__ u64 gt3(u64 a2, u64 a1, u64 a0,
                                   u64 b2, u64 b1, u64 b0)
{
    u64 e2 = ~(a2 ^ b2), g2 = a2 & ~b2;
    u64 e1 = ~(a1 ^ b1), g1 = a1 & ~b1;
    u64 g0 = a0 & ~b0;
    return g2 | (e2 & (g1 | (e1 & g0)));
}

__global__ __launch_bounds__(NT)
void edge_loss_kernel(const float* __restrict__ pred,
                      const float* __restrict__ target,
                      float* __restrict__ partials,
                      u32* __restrict__ done_ctr,
                      float* __restrict__ out,
                      int nblocks, double invN)
{
    __shared__ u64 bl[40 * 16];               // target bits, bl row i = img row r0-4+i
    __shared__ u64 m0[38 * 16], m1[38 * 16], m2[38 * 16]; // m planes, mi = img row r0-3+mi
    __shared__ u64 hz[38 * 16], vt[38 * 16], sdp[38 * 16];
    __shared__ u64 cnd[36 * 16];              // cand, ci = img row r0-2+ci
    __shared__ u64 hrr[36 * 16];              // horiz 5-OR of cand
    __shared__ u64 ezz[RB * 16];              // edge-zone bits for band rows
    __shared__ float wsum[8];
    __shared__ double dsum[8];
    __shared__ u32 lastf;

    const int tid = threadIdx.x;
    const int band = blockIdx.x;
    const int bz = blockIdx.y;
    const int r0 = band * RB;
    const float* pimg = pred + (size_t)bz * H_IMG * W_IMG;
    const float* timg = target + (size_t)bz * H_IMG * W_IMG;

    // ---- Stage 0: binarize target slab (contiguous rows) into bit rows ----
    {
        u8* bl8 = (u8*)bl;
        const float4* tp4 = (const float4*)timg;
#pragma unroll
        for (int j = 0; j < 10; ++j) {        // 40 rows * 128 bytes = 5120
            int bidx = tid + NT * j;
            int row = bidx >> 7;
            int bc = bidx & 127;
            int tr = r0 - 4 + row; tr = tr < 0 ? 0 : (tr > H_IMG - 1 ? H_IMG - 1 : tr);
            int fi = tr * (W_IMG / 4) + bc * 2;
            float4 f0 = tp4[fi], f1 = tp4[fi + 1];
            u32 b = (f0.x > 0.5f ? 1u : 0u)  | (f0.y > 0.5f ? 2u : 0u)
                  | (f0.z > 0.5f ? 4u : 0u)  | (f0.w > 0.5f ? 8u : 0u)
                  | (f1.x > 0.5f ? 16u : 0u) | (f1.y > 0.5f ? 32u : 0u)
                  | (f1.z > 0.5f ? 64u : 0u) | (f1.w > 0.5f ? 128u : 0u);
            bl8[bidx] = (u8)b;
        }
    }
    __syncthreads();

    // ---- Stage A: bit-sliced Sobel -> m planes + class planes ----
    for (int t = tid; t < 38 * 16; t += NT) {
        int mi = t >> 4, w = t & 15;
        const u64* ra = &bl[mi * 16];
        const u64* rb = ra + 16;
        const u64* rc = rb + 16;
        u64 A = ra[w], Bq = rb[w], C = rc[w];
        u64 Acl = w ? (ra[w - 1] >> 63) : (A & 1ULL);
        u64 Bcl = w ? (rb[w - 1] >> 63) : (Bq & 1ULL);
        u64 Ccl = w ? (rc[w - 1] >> 63) : (C & 1ULL);
        u64 Acr = (w < 15) ? (ra[w + 1] << 63) : (A & 0x8000000000000000ULL);
        u64 Bcr = (w < 15) ? (rb[w + 1] << 63) : (Bq & 0x8000000000000000ULL);
        u64 Ccr = (w < 15) ? (rc[w + 1] << 63) : (C & 0x8000000000000000ULL);
        u64 AL = (A << 1) | Acl, AR = (A >> 1) | Acr;
        u64 BL = (Bq << 1) | Bcl, BR = (Bq >> 1) | Bcr;
        u64 CL = (C << 1) | Ccl, CR = (C >> 1) | Ccr;

        u64 sx = AR ^ CR, cxk = AR & CR;
        u64 Px1 = BR ^ cxk, Px2 = BR & cxk;
        u64 sn = AL ^ CL, cnk = AL & CL;
        u64 Nx1 = BL ^ cnk, Nx2 = BL & cnk;
        u64 d0 = sx ^ sn;
        u64 ca = sx | ~sn;
        u64 nb1 = ~Nx1, t1 = Px1 ^ nb1, d1 = t1 ^ ca;
        u64 cb = (Px1 & nb1) | (ca & t1);
        u64 nb2 = ~Nx2, t2 = Px2 ^ nb2, d2 = t2 ^ cb;
        u64 cc = (Px2 & nb2) | (cb & t2);
        u64 sgx = ~cc;                         // gx < 0
        u64 ax0 = d0;
        u64 ax1 = d1 ^ (sgx & d0);
        u64 ax2 = d2 ^ (sgx & (d0 | d1));

        u64 sy = CL ^ CR, cyk = CL & CR;
        u64 Py1 = C ^ cyk, Py2 = C & cyk;
        u64 sm = AL ^ AR, cmk = AL & AR;
        u64 Ny1 = A ^ cmk, Ny2 = A & cmk;
        u64 e0 = sy ^ sm;
        u64 ka = sy | ~sm;
        u64 mb1 = ~Ny1, u1 = Py1 ^ mb1, f1 = u1 ^ ka;
        u64 kb = (Py1 & mb1) | (ka & u1);
        u64 mb2 = ~Ny2, u2 = Py2 ^ mb2, f2 = u2 ^ kb;
        u64 kc = (Py2 & mb2) | (kb & u2);
        u64 sgy = ~kc;                         // gy < 0
        u64 ay0 = e0;
        u64 ay1 = f1 ^ (sgy & e0);
        u64 ay2 = f2 ^ (sgy & (e0 | f1));

        u64 s0 = ax0 ^ ay0, q0 = ax0 & ay0;
        u64 tt = ax1 ^ ay1, s1 = tt ^ q0;
        u64 q1 = (ax1 & ay1) | (q0 & tt);
        u64 s2 = ax2 ^ ay2 ^ q1;
        m0[t] = s0; m1[t] = s1; m2[t] = s2;

        u64 ax12 = ax1 | ax2, axnz = ax0 | ax12;
        u64 axe1 = ax0 & ~ax12, axg3 = ax2 | (ax1 & ax0);
        u64 ay12 = ay1 | ay2, aynz = ay0 | ay12;
        u64 aye1 = ay0 & ~ay12, ayg3 = ay2 | (ay1 & ay0);
        hz[t] = (axnz & ~aynz) | (aye1 & axg3);
        vt[t] = (aynz & ~axnz) | (axe1 & ayg3);
        u64 gxp = axnz & ~sgx, gyp = aynz & ~sgy;
        sdp[t] = (gxp & sgy) | (sgx & gyp);
    }
    __syncthreads();

    // ---- Stage B: bit-sliced NMS + threshold + interior -> cand ----
    for (int t = tid; t < 36 * 16; t += NT) {
        int ci = t >> 4, w = t & 15;
        int iu = ci * 16 + w, im = iu + 16, id = iu + 32;
        u64 M0c = m0[im], M1c = m1[im], M2c = m2[im];
        u64 U0c = m0[iu], U1c = m1[iu], U2c = m2[iu];
        u64 D0c = m0[id], D1c = m1[id], D2c = m2[id];
        u64 M0l = 0, M1l = 0, M2l = 0, U0l = 0, U1l = 0, U2l = 0,
            D0l = 0, D1l = 0, D2l = 0;
        if (w) {
            M0l = m0[im - 1]; M1l = m1[im - 1]; M2l = m2[im - 1];
            U0l = m0[iu - 1]; U1l = m1[iu - 1]; U2l = m2[iu - 1];
            D0l = m0[id - 1]; D1l = m1[id - 1]; D2l = m2[id - 1];
        }
        u64 M0r = 0, M1r = 0, M2r = 0, U0r = 0, U1r = 0, U2r = 0,
            D0r = 0, D1r = 0, D2r = 0;
        if (w < 15) {
            M0r = m0[im + 1]; M1r = m1[im + 1]; M2r = m2[im + 1];
            U0r = m0[iu + 1]; U1r = m1[iu + 1]; U2r = m2[iu + 1];
            D0r = m0[id + 1]; D1r = m1[id + 1]; D2r = m2[id + 1];
        }
        // shifted planes: <<1 = col-1 (carry = left word bit63),
        //                 >>1 = col+1 (carry = right word bit0)
        u64 ML0 = (M0c << 1) | (M0l >> 63), ML1 = (M1c << 1) | (M1l >> 63),
            ML2 = (M2c << 1) | (M2l >> 63);
        u64 MR0 = (M0c >> 1) | (M0r << 63), MR1 = (M1c >> 1) | (M1r << 63),
            MR2 = (M2c >> 1) | (M2r << 63);
        u64 UL0 = (U0c << 1) | (U0l >> 63), UL1 = (U1c << 1) | (U1l >> 63),
            UL2 = (U2c << 1) | (U2l >> 63);
        u64 UR0 = (U0c >> 1) | (U0r << 63), UR1 = (U1c >> 1) | (U1r << 63),
            UR2 = (U2c >> 1) | (U2r << 63);
        u64 DL0 = (D0c << 1) | (D0l >> 63), DL1 = (D1c << 1) | (D1l >> 63),
            DL2 = (D2c << 1) | (D2l >> 63);
        u64 DR0 = (D0c >> 1) | (D0r << 63), DR1 = (D1c >> 1) | (D1r << 63),
            DR2 = (D2c >> 1) | (D2r << 63);

        u64 kH = gt3(M2c, M1c, M0c, ML2, ML1, ML0) &
                ~gt3(MR2, MR1, MR0, M2c, M1c, M0c);
        u64 kV = gt3(M2c, M1c, M0c, U2c, U1c, U0c) &
                ~gt3(D2c, D1c, D0c, M2c, M1c, M0c);
        u64 kA = gt3(M2c, M1c, M0c, UR2, UR1, UR0) &
                ~gt3(DL2, DL1, DL0, M2c, M1c, M0c);
        u64 kB = gt3(M2c, M1c, M0c, UL2, UL1, UL0) &
                ~gt3(DR2, DR1, DR0, M2c, M1c, M0c);

        u64 H = hz[im], V = vt[im], S = sdp[im];
        u64 nHV = ~(H | V);
        u64 keep = (H & kH) | (V & kV) | (nHV & ((S & kA) | (~S & kB)));
        u64 cand = keep & (M0c | M1c | M2c);
        if (w == 0)  cand &= ~1ULL;
        if (w == 15) cand &= ~0x8000000000000000ULL;
        int rr = r0 - 2 + ci;
        if (rr < 1 || rr > H_IMG - 2) cand = 0;
        cnd[t] = cand;
    }
    __syncthreads();

    // ---- Stage C: horizontal 5-OR (0 outside image == 0-pad dilate) ----
    for (int t = tid; t < 36 * 16; t += NT) {
        int w = t & 15;
        u64 c = cnd[t];
        u64 cl = w ? cnd[t - 1] : 0;
        u64 cr = (w < 15) ? cnd[t + 1] : 0;
        hrr[t] = c | (c << 1) | (cl >> 63) | (c << 2) | (cl >> 62)
                   | (c >> 1) | (cr << 63) | (c >> 2) | (cr << 62);
    }
    __syncthreads();

    // ---- Stage C2: vertical 5-OR -> edge-zone bits for band rows ----
    for (int t = tid; t < RB * 16; t += NT)
        ezz[t] = hrr[t] | hrr[t + 16] | hrr[t + 32] | hrr[t + 48] | hrr[t + 64];
    __syncthreads();

    // ---- Stage D: weighted BCE over the contiguous pred slab ----
    float acc = 0.0f;
    {
        const float4* pp4 = (const float4*)(pimg + (size_t)r0 * W_IMG);
#pragma unroll 4
        for (int k = 0; k < 16; ++k) {        // 32 rows * 256 float4 = 8192
            int fi = tid + NT * k;
            float4 pv = pp4[fi];
            int px = fi << 2;
            int row = px >> 10;
            int w = (px >> 6) & 15;
            int sh = px & 63;
            u32 tb = (u32)(bl[(row + 4) * 16 + w] >> sh);
            u32 eb = (u32)(ezz[row * 16 + w] >> sh);
            float ps[4] = {pv.x, pv.y, pv.z, pv.w};
#pragma unroll
            for (int c2 = 0; c2 < 4; ++c2) {
                float p = ps[c2];
                float xx = ((tb >> c2) & 1u) ? p : 1.0f - p;
                float lg = fmaxf(__logf(xx), -100.0f);
                acc = fmaf(((eb >> c2) & 1u) ? 5.0f : 1.0f, -lg, acc);
            }
        }
    }

    for (int off = 32; off > 0; off >>= 1)
        acc += __shfl_down(acc, off);
    int wid = tid >> 6, lane = tid & 63;
    if (lane == 0) wsum[wid] = acc;
    __syncthreads();
    if (tid == 0) {
        float s = 0.0f;
#pragma unroll
        for (int i = 0; i < 8; ++i) s += wsum[i];
        int bi = blockIdx.y * NBANDS + blockIdx.x;
        partials[bi] = s;
        __threadfence();
        u32 r = atomicAdd(done_ctr, 1u);
        lastf = (r == (u32)(nblocks - 1)) ? 1u : 0u;
    }
    __syncthreads();

    // ---- last block: final reduction (deterministic order) ----
    if (lastf) {
        __threadfence();
        double d = 0.0;
        for (int i = tid; i < nblocks; i += NT)
            d += (double)((volatile float*)partials)[i];
        for (int off = 32; off > 0; off >>= 1)
            d += __shfl_down(d, off);
        if (lane == 0) dsum[wid] = d;
        __syncthreads();
        if (tid == 0) {
            double s = 0.0;
#pragma unroll
            for (int i = 0; i < 8; ++i) s += dsum[i];
            out[0] = (float)(s * invN);
            *done_ctr = 0;                    // self-reset for next launch
        }
    }
}

extern "C" void kernel_launch(void* const* d_in, const int* in_sizes, int n_in,
                              void* d_out, int out_size, void* d_ws, size_t ws_size,
                              hipStream_t stream)
{
    (void)n_in; (void)out_size; (void)ws_size;
    const float* pred   = (const float*)d_in[0];
    const float* target = (const float*)d_in[1];
    const int N = in_sizes[0];
    const int B = N / (H_IMG * W_IMG);

    // ws layout: [0,8KB) per-block partials; [8KB] done counter
    float* partials = (float*)d_ws;
    u32* done_ctr = (u32*)((char*)d_ws + 8192);
    hipMemsetAsync(done_ctr, 0, 4, stream);

    dim3 grid(NBANDS, B);
    edge_loss_kernel<<<grid, NT, 0, stream>>>(pred, target, partials, done_ctr,
                                              (float*)d_out, NBANDS * B,
                                              1.0 / (double)N);
}